// Round 8
// baseline (136.012 us; speedup 1.0000x reference)
//
#include <hip/hip_runtime.h>
#include <stdint.h>

// FFM: B=4096, F=20 fields x S=500 feats, K=16.
// E2[b, i*320 + g*16 + k] = sum_s x[b,i*500+s]*v[g,i*500+s,k]
// lin[b] = x[b,:]@w ;  out[b] = lin[b] + sum_{i<j,k} E2[b,i,j,k]*E2[b,j,i,k]

#define NF 20
#define FS 500
#define TFEAT 10000
#define KD 16
#define NC 320          // NF*KD, GEMM N
#define KP 512
#define NB 4096
#define ROWE (NF * NC)  // 6400

typedef __bf16 bf16x8 __attribute__((ext_vector_type(8)));
typedef __bf16 bf16x2 __attribute__((ext_vector_type(2)));
typedef float  f32x4  __attribute__((ext_vector_type(4)));
typedef unsigned int u32x4 __attribute__((ext_vector_type(4)));

typedef __attribute__((address_space(1))) const void* as1cv;
typedef __attribute__((address_space(3))) void* as3v;

__device__ inline void gload_lds16(const void* g, void* l) {
  __builtin_amdgcn_global_load_lds((as1cv)g, (as3v)l, 16, 0, 0);
}

// ---------------- prep: Vt[i][n][kk] = v[g, i*500+kk, k], n=g*16+k, kk<512 (0-padded)
__global__ __launch_bounds__(256) void prep_vt(const float* __restrict__ v,
                                               __bf16* __restrict__ Vt) {
  __shared__ float lv[FS * 17];
  const int i = blockIdx.x / NF;
  const int g = blockIdx.x % NF;
  const int t = threadIdx.x;
  const int k = t & 15, sb = t >> 4;
  const float* vb = v + ((size_t)g * TFEAT + (size_t)i * FS) * KD;
  for (int it = 0; it < 32; ++it) {
    int s = it * 16 + sb;
    if (s < FS) lv[s * 17 + k] = vb[(size_t)s * KD + k];
  }
  __syncthreads();
  __bf16* out = Vt + ((size_t)(i * NC + g * 16)) * KP;
  for (int r = 0; r < 16; ++r) {
    int s0 = 2 * t, s1 = 2 * t + 1;
    bf16x2 pr;
    pr[0] = (s0 < FS) ? (__bf16)lv[s0 * 17 + r] : (__bf16)0.f;
    pr[1] = (s1 < FS) ? (__bf16)lv[s1 * 17 + r] : (__bf16)0.f;
    *(bf16x2*)(out + (size_t)r * KP + 2 * t) = pr;
  }
}

// ---------------- K1: per-field GEMM + fused linear. BM=128, BN=320, BK=32,
// 512 threads = 8 waves (2M x 4N), wave tile 64x80, acc[4][5]=80 VGPR (balanced).
// A: reg-staged bf16 dbuf [2][128][32]; B: glds-staged dbuf [2][320*32]; w in LDS.
// XOR swizzles (0 conflicts, verified R6/R7). One vmcnt(0)+lgkmcnt(0)+barrier/iter.
// LDS 59.3 KB -> 2 blocks/CU = 16 waves/CU (needs VGPR <= 128).
__global__ __launch_bounds__(512, 4) void k1_gemm(
    const float* __restrict__ x, const float* __restrict__ w,
    const __bf16* __restrict__ Vt, __bf16* __restrict__ E2,
    float* __restrict__ lin, int chunk_base, int tiles) {
  __shared__ __bf16 As[2][128][32];     // 16384 B
  __shared__ __bf16 Bs[2][NC * 32];     // 40960 B
  __shared__ float wlds[FS];            // 2000 B

  const int bx = blockIdx.x;
  const int i  = bx / tiles;
  const int tb = bx % tiles;
  const int tid = threadIdx.x;
  const int lane = tid & 63, wid = tid >> 6;
  const int wm = wid >> 2, wn = wid & 3;
  const int b0 = chunk_base + tb * 128;

  // A stage (per thread): row = tid>>2 (0..127), 8 cols at (tid&3)*8, swizzled chunk
  const int arow = tid >> 2;
  const int ac8 = (tid & 3) * 8;
  const int apch = (tid & 3) ^ ((tid >> 3) & 3);   // (tid&3) ^ ((arow>>1)&3)
  const float* xrow = x + (size_t)(b0 + arow) * TFEAT + i * FS;
  // B stage: instr q covers 16 rows x 4 chunks; src chunk pre-swizzled
  const int brow_off = lane >> 2;
  const int blc8 = ((lane & 3) ^ ((lane >> 3) & 3)) * 8;
  const __bf16* VtB = Vt + (size_t)i * NC * KP;

  auto issueB = [&](int t, int buf) {
    int soffB = t * 32 + blc8;
#pragma unroll
    for (int jj = 0; jj < 3; ++jj) {
      int q = wid + 8 * jj;
      if (q < 20)
        gload_lds16(VtB + (size_t)(16 * q + brow_off) * KP + soffB,
                    (void*)&Bs[buf][q * 512]);
    }
  };

  f32x4 ar0, ar1;
  float lp = 0.f;
  auto aload = [&](int t) {
    int kk = t * 32 + ac8;
    int c0 = kk > 496 ? 496 : kk;          // clamp: junk cols pair with zero B rows
    int c1 = kk + 4 > 496 ? 496 : kk + 4;
    ar0 = *(const f32x4*)(xrow + c0);
    ar1 = *(const f32x4*)(xrow + c1);
  };
  auto astore = [&](int t, int buf) {
    int kk = t * 32 + ac8;
    int c0 = kk > 496 ? 496 : kk;
    int c1 = kk + 4 > 496 ? 496 : kk + 4;
    if (kk <= 496) {                       // cols kk..kk+3 valid (<500)
      f32x4 wv = *(const f32x4*)(wlds + c0);
      lp += ar0[0] * wv[0] + ar0[1] * wv[1] + ar0[2] * wv[2] + ar0[3] * wv[3];
    }
    if (kk + 4 <= 496) {                   // cols kk+4..kk+7 valid
      f32x4 wv = *(const f32x4*)(wlds + c1);
      lp += ar1[0] * wv[0] + ar1[1] * wv[1] + ar1[2] * wv[2] + ar1[3] * wv[3];
    }
    bf16x8 h;
    h[0] = (__bf16)ar0[0]; h[1] = (__bf16)ar0[1];
    h[2] = (__bf16)ar0[2]; h[3] = (__bf16)ar0[3];
    h[4] = (__bf16)ar1[0]; h[5] = (__bf16)ar1[1];
    h[6] = (__bf16)ar1[2]; h[7] = (__bf16)ar1[3];
    *(bf16x8*)(&As[buf][arow][apch * 8]) = h;
  };

  const int ar = lane & 15, akc = lane >> 4;

  f32x4 acc[4][5];
#pragma unroll
  for (int m = 0; m < 4; ++m)
#pragma unroll
    for (int nf = 0; nf < 5; ++nf) acc[m][nf] = (f32x4){0.f, 0.f, 0.f, 0.f};

  // prologue
  for (int c = tid; c < FS; c += 512) wlds[c] = w[i * FS + c];
  aload(0);
  issueB(0, 0);
  asm volatile("s_waitcnt lgkmcnt(0)" ::: "memory");
  __builtin_amdgcn_s_barrier();          // wlds visible
  astore(0, 0);                          // waits own x regs; reads wlds; writes As[0]
  asm volatile("s_waitcnt vmcnt(0) lgkmcnt(0)" ::: "memory");
  __builtin_amdgcn_s_barrier();          // B(0) + As[0] ready

  for (int t = 0; t < 16; ++t) {
    const int cur = t & 1;
    if (t < 15) {
      aload(t + 1);                      // global->reg
      issueB(t + 1, cur ^ 1);            // glds into other buffer
    }
    __builtin_amdgcn_sched_barrier(0);

    bf16x8 af[4];
#pragma unroll
    for (int m = 0; m < 4; ++m) {
      int row = wm * 64 + m * 16 + ar;
      int pch = akc ^ ((row >> 1) & 3);
      af[m] = *(const bf16x8*)(&As[cur][row][pch * 8]);
    }
#pragma unroll
    for (int nf = 0; nf < 5; ++nf) {
      int n_ = (wn * 5 + nf) * 16 + ar;
      int pc = akc ^ ((n_ >> 1) & 3);
      bf16x8 bfr = *(const bf16x8*)&Bs[cur][n_ * 32 + pc * 8];
#pragma unroll
      for (int m = 0; m < 4; ++m)
        acc[m][nf] = __builtin_amdgcn_mfma_f32_16x16x32_bf16(af[m], bfr,
                                                             acc[m][nf], 0, 0, 0);
    }
    if (t < 15) {
      astore(t + 1, cur ^ 1);            // cvt+lin FMA+ds_write other buffer
      asm volatile("s_waitcnt vmcnt(0) lgkmcnt(0)" ::: "memory");
      __builtin_amdgcn_s_barrier();
    }
  }

  // linear partial: 4 consecutive lanes share a row
  lp += __shfl_xor(lp, 1);
  lp += __shfl_xor(lp, 2);
  if ((tid & 3) == 0) atomicAdd(&lin[b0 + arow], lp);

  // epilogue: C/D layout col=lane&15, row=(lane>>4)*4+r
  const int lr4 = akc * 4;
#pragma unroll
  for (int m = 0; m < 4; ++m)
#pragma unroll
    for (int nf = 0; nf < 5; ++nf) {
      int n = (wn * 5 + nf) * 16 + ar;
#pragma unroll
      for (int r = 0; r < 4; ++r) {
        int bl = tb * 128 + wm * 64 + m * 16 + lr4 + r;
        E2[(size_t)bl * ROWE + i * NC + n] = (__bf16)acc[m][nf][r];
      }
    }
}

// ---------------- K2: pair reduction + lin, 1 wave per batch row
__global__ __launch_bounds__(256) void k2_pair(
    const __bf16* __restrict__ E2, const float* __restrict__ lin,
    float* __restrict__ out, int chunk_base) {
  __shared__ __align__(16) unsigned shw[4][3200];  // 12.8 KB per wave
  const int tid = threadIdx.x, lane = tid & 63, wid = tid >> 6;
  const int bl = blockIdx.x * 4 + wid;
  const unsigned* src = (const unsigned*)(E2 + (size_t)bl * ROWE);
  for (int it = 0; it < 13; ++it) {
    int idx = it * 64 + lane;             // 16B units; 800 total
    if (idx < 800) {
      u32x4 val = *(const u32x4*)(src + (size_t)idx * 4);
      *(u32x4*)&shw[wid][idx * 4] = val;
    }
  }
  __syncthreads();
  const __bf16* sh = (const __bf16*)shw[wid];
  const int k = lane & 15, g = lane >> 4;
  float sum = 0.f;
  for (int i = g; i < NF; i += 4)
    for (int j = i + 1; j < NF; ++j)
      sum += (float)sh[i * NC + j * 16 + k] * (float)sh[j * NC + i * 16 + k];
#pragma unroll
  for (int off = 32; off; off >>= 1) sum += __shfl_xor(sum, off);
  if (lane == 0) {
    int bg = chunk_base + bl;
    out[bg] = lin[bg] + sum;
  }
}

extern "C" void kernel_launch(void* const* d_in, const int* in_sizes, int n_in,
                              void* d_out, int out_size, void* d_ws, size_t ws_size,
                              hipStream_t stream) {
  const float* x = (const float*)d_in[0];
  const float* w = (const float*)d_in[1];
  const float* v = (const float*)d_in[2];
  float* out = (float*)d_out;
  char* ws = (char*)d_ws;

  const size_t vt_bytes = (size_t)NF * NC * KP * 2;     // 6,553,600
  __bf16* Vt = (__bf16*)ws;
  float* lin = (float*)(ws + vt_bytes);                 // 16,384 B
  __bf16* E2 = (__bf16*)(ws + vt_bytes + 16384);

  size_t eavail = (ws_size > vt_bytes + 16384) ? ws_size - vt_bytes - 16384 : 0;
  int Bc = NB;
  while (Bc > 128 && (size_t)Bc * ROWE * 2 > eavail) Bc >>= 1;

  hipMemsetAsync(lin, 0, NB * sizeof(float), stream);
  prep_vt<<<NF * NF, 256, 0, stream>>>(v, Vt);
  for (int cb = 0; cb < NB; cb += Bc) {
    int tiles = Bc / 128;
    k1_gemm<<<NF * tiles, 512, 0, stream>>>(x, w, Vt, E2, lin, cb, tiles);
    k2_pair<<<Bc / 4, 256, 0, stream>>>(E2, lin, out, cb);
  }
}

// Round 9
// 80.679 us; speedup vs baseline: 1.6858x; 1.6858x over previous
//
#include <hip/hip_runtime.h>
#include <stdint.h>

// FFM: B=4096, F=20 fields x S=500 feats, K=16.
// E2[b, i*336 + g*16 + k] = sum_s x[b,i*500+s]*v[g,i*500+s,k]  (g<20)
// E2[b, i*336 + 320]      = sum_s x[b,i*500+s]*w[i*500+s]      (linear partial)
// out[b] = sum_i E2[b,i,320] + sum_{i<j,k} E2[b,i*336+j*16+k]*E2[b,j*336+i*16+k]

#define NF 20
#define FS 500
#define TFEAT 10000
#define KD 16
#define NCOL 336        // 21 frags: 320 interaction cols + 16-col w block
#define NFRG 21
#define KP 512
#define NB 4096
#define ROWE (NF * NCOL)  // 6720

typedef __bf16 bf16x8 __attribute__((ext_vector_type(8)));
typedef __bf16 bf16x2 __attribute__((ext_vector_type(2)));
typedef float  f32x4  __attribute__((ext_vector_type(4)));
typedef unsigned int u32x4 __attribute__((ext_vector_type(4)));

typedef __attribute__((address_space(1))) const void* as1cv;
typedef __attribute__((address_space(3))) void* as3v;

__device__ inline void gload_lds16(const void* g, void* l) {
  __builtin_amdgcn_global_load_lds((as1cv)g, (as3v)l, 16, 0, 0);
}

// ---------------- prep: VtS in STAGED order. VtS[((i*16+t)*21+q)*512 + l*8 + e]
// = B-panel value for row n=16q+(l>>2), k-elem kk = t*32 + ((l&3)^((l>>3)&3))*8 + e.
// Rows n<320: n=g*16+k -> v[g, i*500+kk, k]; row 320 -> w[i*500+kk]; else 0.
// This makes every k1 B-staging glds a CONTIGUOUS 1 KB read (base + lane*16).
__global__ __launch_bounds__(256) void prep_vt(const float* __restrict__ v,
                                               const float* __restrict__ w,
                                               __bf16* __restrict__ VtS) {
  const int i = blockIdx.x / NFRG;
  const int q = blockIdx.x % NFRG;
  const int tdx = threadIdx.x;
  __shared__ float lv[FS * 17];
  if (q < NF) {  // panel for g=q: lv[s*17+k] = v[g, i*500+s, k]
    const int k = tdx & 15, sb = tdx >> 4;
    const float* vb = v + ((size_t)q * TFEAT + (size_t)i * FS) * KD;
    for (int it = 0; it < 32; ++it) {
      int s = it * 16 + sb;
      if (s < FS) lv[s * 17 + k] = vb[(size_t)s * KD + k];
    }
    __syncthreads();
  }
  const float* wf = w + (size_t)i * FS;
  __bf16* base = VtS + ((size_t)i * 16 * NFRG + q) * 512;
  for (int it = 0; it < 4; ++it) {
    int p = it * 256 + tdx;            // (t,l) pair: 16*64 = 1024
    int t = p >> 6, l = p & 63;
    int r = l >> 2;                    // row within group (= k for q<20)
    int kk = t * 32 + (((l & 3) ^ ((l >> 3) & 3)) << 3);
    bf16x8 h;
#pragma unroll
    for (int e = 0; e < 8; ++e) {
      int s = kk + e;
      float val = 0.f;
      if (s < FS) {
        if (q < NF) val = lv[s * 17 + r];
        else if (r == 0) val = wf[s];
      }
      h[e] = (__bf16)val;
    }
    *(bf16x8*)(base + (size_t)t * (NFRG * 512) + l * 8) = h;
  }
}

// ---------------- K1: per-field GEMM. BM=64, BN=336, BK=32, 16 steps, 4 waves.
// A: reg-staged bf16 dbuf (T14: load x->regs at top, cvt+ds_write after compute).
// B: glds dbuf from STAGED VtS -- each instr reads 1 KB contiguous.
// LDS 51.2 KB -> 3 blocks/CU. One vmcnt(0)+lgkmcnt(0)+barrier per iter.
__global__ __launch_bounds__(256, 3) void k1_gemm(
    const float* __restrict__ x, const __bf16* __restrict__ VtS,
    __bf16* __restrict__ E2, int chunk_base, int tiles) {
  __shared__ __bf16 As[2][64][32];        // 8192 B
  __shared__ __bf16 Bs[2][NCOL * 32];     // 43008 B

  const int bx = blockIdx.x;
  const int i  = bx / tiles;
  const int tb = bx % tiles;
  const int tid = threadIdx.x;
  const int lane = tid & 63, wid = tid >> 6;
  const int b0 = chunk_base + tb * 64;

  // A stage (per thread): row = tid>>2, 8 cols at (tid&3)*8; swizzled chunk
  const int arow = tid >> 2;
  const int ac8 = (tid & 3) * 8;
  const int apch = (tid & 3) ^ ((tid >> 3) & 3);
  const float* xrow = x + (size_t)(b0 + arow) * TFEAT + i * FS;
  const __bf16* VtSi = VtS + (size_t)i * 16 * NFRG * 512 + lane * 8;

  auto issueB = [&](int t, int buf) {
#pragma unroll
    for (int jj = 0; jj < 6; ++jj) {
      int q = wid + 4 * jj;
      if (q < NFRG)
        gload_lds16(VtSi + ((size_t)t * NFRG + q) * 512,
                    (void*)&Bs[buf][q * 512]);
    }
  };

  f32x4 ar0, ar1;
  auto aload = [&](int t) {
    int kk = t * 32 + ac8;
    int c0 = kk > 496 ? 496 : kk;          // clamp: junk cols pair with zero B rows
    int c1 = kk + 4 > 496 ? 496 : kk + 4;
    ar0 = *(const f32x4*)(xrow + c0);
    ar1 = *(const f32x4*)(xrow + c1);
  };
  auto astore = [&](int buf) {
    bf16x8 h;
    h[0] = (__bf16)ar0[0]; h[1] = (__bf16)ar0[1];
    h[2] = (__bf16)ar0[2]; h[3] = (__bf16)ar0[3];
    h[4] = (__bf16)ar1[0]; h[5] = (__bf16)ar1[1];
    h[6] = (__bf16)ar1[2]; h[7] = (__bf16)ar1[3];
    *(bf16x8*)(&As[buf][arow][apch * 8]) = h;
  };

  const int nfr = wid ? 5 : 6;
  const int Fbase = wid ? (1 + wid * 5) : 0;
  const int ar = lane & 15, akc = lane >> 4;

  f32x4 acc[4][6];
#pragma unroll
  for (int m = 0; m < 4; ++m)
#pragma unroll
    for (int nf = 0; nf < 6; ++nf) acc[m][nf] = (f32x4){0.f, 0.f, 0.f, 0.f};

  // prologue
  aload(0);
  issueB(0, 0);
  astore(0);
  asm volatile("s_waitcnt vmcnt(0) lgkmcnt(0)" ::: "memory");
  __builtin_amdgcn_s_barrier();

  for (int t = 0; t < 16; ++t) {
    const int cur = t & 1;
    if (t < 15) {
      aload(t + 1);                 // global->reg (HBM stream)
      issueB(t + 1, cur ^ 1);       // 5-6 contiguous 1KB glds into other buffer
    }
    __builtin_amdgcn_sched_barrier(0);

    bf16x8 bfr[6];
#pragma unroll
    for (int nf = 0; nf < 6; ++nf)
      if (nf < nfr) {
        int n_ = (Fbase + nf) * 16 + ar;
        int pc = akc ^ ((n_ >> 1) & 3);
        bfr[nf] = *(const bf16x8*)&Bs[cur][n_ * 32 + pc * 8];
      }
#pragma unroll
    for (int m = 0; m < 4; ++m) {
      int row = m * 16 + ar;
      int pch = akc ^ ((row >> 1) & 3);
      bf16x8 af = *(const bf16x8*)(&As[cur][row][pch * 8]);
#pragma unroll
      for (int nf = 0; nf < 6; ++nf)
        if (nf < nfr)
          acc[m][nf] = __builtin_amdgcn_mfma_f32_16x16x32_bf16(af, bfr[nf],
                                                               acc[m][nf], 0, 0, 0);
    }
    if (t < 15) {
      astore(cur ^ 1);              // cvt+ds_write; waits own A regs
      asm volatile("s_waitcnt vmcnt(0) lgkmcnt(0)" ::: "memory");
      __builtin_amdgcn_s_barrier();
    }
  }

  // epilogue: C/D layout col=lane&15, row=(lane>>4)*4+r
  const int lr4 = akc * 4, lcol = lane & 15;
#pragma unroll
  for (int m = 0; m < 4; ++m)
#pragma unroll
    for (int nf = 0; nf < 6; ++nf)
      if (nf < nfr) {
        int n = (Fbase + nf) * 16 + lcol;
#pragma unroll
        for (int r = 0; r < 4; ++r) {
          int bl = tb * 64 + m * 16 + lr4 + r;
          E2[(size_t)bl * ROWE + i * NCOL + n] = (__bf16)acc[m][nf][r];
        }
      }
}

// ---------------- K2: pair + linear reduction, 1 wave per batch row
__global__ __launch_bounds__(256) void k2_pair(
    const __bf16* __restrict__ E2, float* __restrict__ out, int chunk_base) {
  __shared__ __align__(16) unsigned shw[4][3360];  // 13440 B per wave
  const int tid = threadIdx.x, lane = tid & 63, wid = tid >> 6;
  const int bl = blockIdx.x * 4 + wid;
  const unsigned* src = (const unsigned*)(E2 + (size_t)bl * ROWE);
  for (int it = 0; it < 14; ++it) {
    int idx = it * 64 + lane;             // 16B units; 840 total
    if (idx < 840) {
      u32x4 val = *(const u32x4*)(src + (size_t)idx * 4);
      *(u32x4*)&shw[wid][idx * 4] = val;
    }
  }
  __syncthreads();
  const __bf16* sh = (const __bf16*)shw[wid];
  const int k = lane & 15, g = lane >> 4;
  float sum = 0.f;
  for (int i = g; i < NF; i += 4)
    for (int j = i + 1; j < NF; ++j)
      sum += (float)sh[i * NCOL + j * 16 + k] * (float)sh[j * NCOL + i * 16 + k];
  if (lane < NF) sum += (float)sh[lane * NCOL + 320];   // linear term
#pragma unroll
  for (int off = 32; off; off >>= 1) sum += __shfl_xor(sum, off);
  if (lane == 0) out[chunk_base + bl] = sum;
}

extern "C" void kernel_launch(void* const* d_in, const int* in_sizes, int n_in,
                              void* d_out, int out_size, void* d_ws, size_t ws_size,
                              hipStream_t stream) {
  const float* x = (const float*)d_in[0];
  const float* w = (const float*)d_in[1];
  const float* v = (const float*)d_in[2];
  float* out = (float*)d_out;
  char* ws = (char*)d_ws;

  const size_t vt_bytes = (size_t)NF * 16 * NFRG * 512 * 2;   // 6,881,280
  __bf16* VtS = (__bf16*)ws;
  __bf16* E2 = (__bf16*)(ws + vt_bytes);

  size_t eavail = (ws_size > vt_bytes) ? ws_size - vt_bytes : 0;
  int Bc = NB;
  while (Bc > 64 && (size_t)Bc * ROWE * 2 > eavail) Bc >>= 1;

  prep_vt<<<NF * NFRG, 256, 0, stream>>>(v, w, VtS);
  for (int cb = 0; cb < NB; cb += Bc) {
    int tiles = Bc / 64;
    k1_gemm<<<NF * tiles, 256, 0, stream>>>(x, VtS, E2, cb, tiles);
    k2_pair<<<Bc / 4, 256, 0, stream>>>(E2, out, cb);
  }
}

// Round 10
// 76.760 us; speedup vs baseline: 1.7719x; 1.0511x over previous
//
#include <hip/hip_runtime.h>
#include <stdint.h>

// FFM: B=4096, F=20 fields x S=500 feats, K=16.
// E2[b, i*336 + g*16 + k] = sum_s x[b,i*500+s]*v[g,i*500+s,k]  (g<20)
// E2[b, i*336 + 320]      = sum_s x[b,i*500+s]*w[i*500+s]      (linear partial)
// out[b] = sum_i E2[b,i,320] + sum_{i<j,k} E2[b,i*336+j*16+k]*E2[b,j*336+i*16+k]

#define NF 20
#define FS 500
#define TFEAT 10000
#define KD 16
#define NCOL 336        // 21 frags: 320 interaction cols + 16-col w block
#define NFRG 21
#define KP 512
#define NB 4096
#define ROWE (NF * NCOL)  // 6720

typedef __bf16 bf16x8 __attribute__((ext_vector_type(8)));
typedef __bf16 bf16x2 __attribute__((ext_vector_type(2)));
typedef float  f32x4  __attribute__((ext_vector_type(4)));
typedef unsigned int u32x4 __attribute__((ext_vector_type(4)));

typedef __attribute__((address_space(1))) const void* as1cv;
typedef __attribute__((address_space(3))) void* as3v;

__device__ inline void gload_lds16(const void* g, void* l) {
  __builtin_amdgcn_global_load_lds((as1cv)g, (as3v)l, 16, 0, 0);
}

// ---------------- prep: VtS in STAGED order. VtS[((i*16+t)*21+q)*512 + l*8 + e]
// = B-panel value for row n=16q+(l>>2), k-elem kk = t*32 + ((l&3)^((l>>3)&3))*8 + e.
// Rows n<320: n=g*16+k -> v[g, i*500+kk, k]; row 320 -> w[i*500+kk]; else 0.
__global__ __launch_bounds__(256) void prep_vt(const float* __restrict__ v,
                                               const float* __restrict__ w,
                                               __bf16* __restrict__ VtS) {
  const int i = blockIdx.x / NFRG;
  const int q = blockIdx.x % NFRG;
  const int tdx = threadIdx.x;
  __shared__ float lv[FS * 17];
  if (q < NF) {  // panel for g=q: lv[s*17+k] = v[g, i*500+s, k]
    const int k = tdx & 15, sb = tdx >> 4;
    const float* vb = v + ((size_t)q * TFEAT + (size_t)i * FS) * KD;
    for (int it = 0; it < 32; ++it) {
      int s = it * 16 + sb;
      if (s < FS) lv[s * 17 + k] = vb[(size_t)s * KD + k];
    }
    __syncthreads();
  }
  const float* wf = w + (size_t)i * FS;
  __bf16* base = VtS + ((size_t)i * 16 * NFRG + q) * 512;
  for (int it = 0; it < 4; ++it) {
    int p = it * 256 + tdx;            // (t,l) pair: 16*64 = 1024
    int t = p >> 6, l = p & 63;
    int r = l >> 2;                    // row within group (= k for q<20)
    int kk = t * 32 + (((l & 3) ^ ((l >> 3) & 3)) << 3);
    bf16x8 h;
#pragma unroll
    for (int e = 0; e < 8; ++e) {
      int s = kk + e;
      float val = 0.f;
      if (s < FS) {
        if (q < NF) val = lv[s * 17 + r];
        else if (r == 0) val = wf[s];
      }
      h[e] = (__bf16)val;
    }
    *(bf16x8*)(base + (size_t)t * (NFRG * 512) + l * 8) = h;
  }
}

// ---------------- K1: per-field GEMM. BM=64, BN=336, BK=32, 16 steps, 4 waves.
// A: reg ping-pong prefetch distance 2 (iter t loads tile t+2; astore(t+1) uses
//    regs ~1.3 iters old -> HBM latency covered).
// B: glds dbuf from STAGED VtS (1 KB contiguous per instr), issued first each iter.
// Drain: s_waitcnt vmcnt(2) -- retires B, leaves newest 2 A loads in flight.
// XCD swizzle: each XCD owns a contiguous logical range (~2.5 fields' panels).
// LDS 51.2 KB -> 3 blocks/CU. 0 bank conflicts (verified R6-R9).
__global__ __launch_bounds__(256, 3) void k1_gemm(
    const float* __restrict__ x, const __bf16* __restrict__ VtS,
    __bf16* __restrict__ E2, int chunk_base, int tiles) {
  __shared__ __bf16 As[2][64][32];        // 8192 B
  __shared__ __bf16 Bs[2][NCOL * 32];     // 43008 B

  int bid = blockIdx.x;
  const int nwg = gridDim.x;
  if ((nwg & 7) == 0) {                   // bijective XCD swizzle
    int cpx = nwg >> 3;
    bid = (bid & 7) * cpx + (bid >> 3);
  }
  const int i  = bid / tiles;
  const int tb = bid % tiles;
  const int tid = threadIdx.x;
  const int lane = tid & 63, wid = tid >> 6;
  const int b0 = chunk_base + tb * 64;

  // A stage (per thread): row = tid>>2, 8 cols at (tid&3)*8; swizzled chunk
  const int arow = tid >> 2;
  const int ac8 = (tid & 3) * 8;
  const int apch = (tid & 3) ^ ((tid >> 3) & 3);
  const float* xrow = x + (size_t)(b0 + arow) * TFEAT + i * FS;
  const __bf16* VtSi = VtS + (size_t)i * 16 * NFRG * 512 + lane * 8;

  auto issueB = [&](int t, int buf) {
#pragma unroll
    for (int jj = 0; jj < 6; ++jj) {
      int q = wid + 4 * jj;
      if (q < NFRG)
        gload_lds16(VtSi + ((size_t)t * NFRG + q) * 512,
                    (void*)&Bs[buf][q * 512]);
    }
  };

  f32x4 a0A, a1A, a0B, a1B;   // two named prefetch sets (static indexing)
  auto aload = [&](int t, f32x4& r0, f32x4& r1) {
    int kk = t * 32 + ac8;
    int c0 = kk > 496 ? 496 : kk;          // clamp: junk cols pair with zero B rows
    int c1 = kk + 4 > 496 ? 496 : kk + 4;
    r0 = *(const f32x4*)(xrow + c0);
    r1 = *(const f32x4*)(xrow + c1);
  };
  auto astore = [&](int buf, const f32x4& r0, const f32x4& r1) {
    bf16x8 h;
    h[0] = (__bf16)r0[0]; h[1] = (__bf16)r0[1];
    h[2] = (__bf16)r0[2]; h[3] = (__bf16)r0[3];
    h[4] = (__bf16)r1[0]; h[5] = (__bf16)r1[1];
    h[6] = (__bf16)r1[2]; h[7] = (__bf16)r1[3];
    *(bf16x8*)(&As[buf][arow][apch * 8]) = h;
  };

  const int nfr = wid ? 5 : 6;
  const int Fbase = wid ? (1 + wid * 5) : 0;
  const int ar = lane & 15, akc = lane >> 4;

  f32x4 acc[4][6];
#pragma unroll
  for (int m = 0; m < 4; ++m)
#pragma unroll
    for (int nf = 0; nf < 6; ++nf) acc[m][nf] = (f32x4){0.f, 0.f, 0.f, 0.f};

  // prologue: tile0 -> As[0]; B(0) staged; aload(1) (set B) left in flight
  aload(0, a0A, a1A);
  astore(0, a0A, a1A);            // waits its own loads (prologue only)
  issueB(0, 0);
  aload(1, a0B, a1B);             // newest: stays in flight across drain
  asm volatile("s_waitcnt vmcnt(2) lgkmcnt(0)" ::: "memory");
  __builtin_amdgcn_s_barrier();

  auto body = [&](int T, int curbuf, f32x4& la0, f32x4& la1,
                  f32x4& sa0, f32x4& sa1) {
    if (T < 15) issueB(T + 1, curbuf ^ 1);         // 6 contiguous glds (older)
    if (T < 14) aload(T + 2, la0, la1);            // 2 loads (newest, stay in flight)
    __builtin_amdgcn_sched_barrier(0);

    bf16x8 bfr[6];
#pragma unroll
    for (int nf = 0; nf < 6; ++nf)
      if (nf < nfr) {
        int n_ = (Fbase + nf) * 16 + ar;
        int pc = akc ^ ((n_ >> 1) & 3);
        bfr[nf] = *(const bf16x8*)&Bs[curbuf][n_ * 32 + pc * 8];
      }
#pragma unroll
    for (int m = 0; m < 4; ++m) {
      int row = m * 16 + ar;
      int pch = akc ^ ((row >> 1) & 3);
      bf16x8 af = *(const bf16x8*)(&As[curbuf][row][pch * 8]);
#pragma unroll
      for (int nf = 0; nf < 6; ++nf)
        if (nf < nfr)
          acc[m][nf] = __builtin_amdgcn_mfma_f32_16x16x32_bf16(af, bfr[nf],
                                                               acc[m][nf], 0, 0, 0);
    }
    if (T < 15) {
      astore(curbuf ^ 1, sa0, sa1);    // regs ~1.3 iters old; wait ~free
      if (T < 14)
        asm volatile("s_waitcnt vmcnt(2) lgkmcnt(0)" ::: "memory");  // counted
      else
        asm volatile("s_waitcnt vmcnt(0) lgkmcnt(0)" ::: "memory");  // tail
      __builtin_amdgcn_s_barrier();
    }
  };

  for (int tt = 0; tt < 16; tt += 2) {
    body(tt,     0, a0A, a1A, a0B, a1B);   // load set0 (tile tt+2), store set1
    body(tt + 1, 1, a0B, a1B, a0A, a1A);   // load set1 (tile tt+3), store set0
  }

  // epilogue: C/D layout col=lane&15, row=(lane>>4)*4+r
  const int lr4 = akc * 4, lcol = lane & 15;
#pragma unroll
  for (int m = 0; m < 4; ++m)
#pragma unroll
    for (int nf = 0; nf < 6; ++nf)
      if (nf < nfr) {
        int n = (Fbase + nf) * 16 + lcol;
#pragma unroll
        for (int r = 0; r < 4; ++r) {
          int bl = tb * 64 + m * 16 + lr4 + r;
          E2[(size_t)bl * ROWE + i * NCOL + n] = (__bf16)acc[m][nf][r];
        }
      }
}

// ---------------- K2: pair + linear reduction, 1 wave per batch row
__global__ __launch_bounds__(256) void k2_pair(
    const __bf16* __restrict__ E2, float* __restrict__ out, int chunk_base) {
  __shared__ __align__(16) unsigned shw[4][3360];  // 13440 B per wave
  const int tid = threadIdx.x, lane = tid & 63, wid = tid >> 6;
  const int bl = blockIdx.x * 4 + wid;
  const unsigned* src = (const unsigned*)(E2 + (size_t)bl * ROWE);
  for (int it = 0; it < 14; ++it) {
    int idx = it * 64 + lane;             // 16B units; 840 total
    if (idx < 840) {
      u32x4 val = *(const u32x4*)(src + (size_t)idx * 4);
      *(u32x4*)&shw[wid][idx * 4] = val;
    }
  }
  __syncthreads();
  const __bf16* sh = (const __bf16*)shw[wid];
  const int k = lane & 15, g = lane >> 4;
  float sum = 0.f;
  for (int i = g; i < NF; i += 4)
    for (int j = i + 1; j < NF; ++j)
      sum += (float)sh[i * NCOL + j * 16 + k] * (float)sh[j * NCOL + i * 16 + k];
  if (lane < NF) sum += (float)sh[lane * NCOL + 320];   // linear term
#pragma unroll
  for (int off = 32; off; off >>= 1) sum += __shfl_xor(sum, off);
  if (lane == 0) out[chunk_base + bl] = sum;
}

extern "C" void kernel_launch(void* const* d_in, const int* in_sizes, int n_in,
                              void* d_out, int out_size, void* d_ws, size_t ws_size,
                              hipStream_t stream) {
  const float* x = (const float*)d_in[0];
  const float* w = (const float*)d_in[1];
  const float* v = (const float*)d_in[2];
  float* out = (float*)d_out;
  char* ws = (char*)d_ws;

  const size_t vt_bytes = (size_t)NF * 16 * NFRG * 512 * 2;   // 6,881,280
  __bf16* VtS = (__bf16*)ws;
  __bf16* E2 = (__bf16*)(ws + vt_bytes);

  size_t eavail = (ws_size > vt_bytes) ? ws_size - vt_bytes : 0;
  int Bc = NB;
  while (Bc > 64 && (size_t)Bc * ROWE * 2 > eavail) Bc >>= 1;

  prep_vt<<<NF * NFRG, 256, 0, stream>>>(v, w, VtS);
  for (int cb = 0; cb < NB; cb += Bc) {
    int tiles = Bc / 64;
    k1_gemm<<<NF * tiles, 256, 0, stream>>>(x, VtS, E2, cb, tiles);
    k2_pair<<<Bc / 4, 256, 0, stream>>>(E2, out, cb);
  }
}

// Round 12
// 72.598 us; speedup vs baseline: 1.8735x; 1.0573x over previous
//
#include <hip/hip_runtime.h>
#include <stdint.h>

// FFM: B=4096, F=20 fields x S=500 feats, K=16.
// E2[b, i*336 + g*16 + k] = sum_s x[b,i*500+s]*v[g,i*500+s,k]  (g<20)
// E2[b, i*336 + 320]      = sum_s x[b,i*500+s]*w[i*500+s]      (linear partial)
// out[b] = sum_i E2[b,i,320] + sum_{i<j,k} E2[b,i*336+j*16+k]*E2[b,j*336+i*16+k]

#define NF 20
#define FS 500
#define TFEAT 10000
#define KD 16
#define NCOL 336        // 21 frags: 320 interaction cols + 16-col w block
#define NFRG 21
#define KP 512
#define NB 4096
#define ROWE (NF * NCOL)  // 6720

typedef __bf16 bf16x8 __attribute__((ext_vector_type(8)));
typedef __bf16 bf16x2 __attribute__((ext_vector_type(2)));
typedef float  f32x4  __attribute__((ext_vector_type(4)));
typedef unsigned int u32x4 __attribute__((ext_vector_type(4)));

typedef __attribute__((address_space(1))) const void* as1cv;
typedef __attribute__((address_space(3))) void* as3v;

__device__ inline void gload_lds16(const void* g, void* l) {
  __builtin_amdgcn_global_load_lds((as1cv)g, (as3v)l, 16, 0, 0);
}

// ---------------- prep: VtS in STAGED order (unchanged from R9/R10).
// VtS[((i*16+t32)*21+q)*512 + l*8 + e] = B-panel value for row n=16q+(l>>2),
// kk = t32*32 + ((l&3)^((l>>3)&3))*8 + e.  n<320 -> v; n==320 -> w; else 0.
__global__ __launch_bounds__(256) void prep_vt(const float* __restrict__ v,
                                               const float* __restrict__ w,
                                               __bf16* __restrict__ VtS) {
  const int i = blockIdx.x / NFRG;
  const int q = blockIdx.x % NFRG;
  const int tdx = threadIdx.x;
  __shared__ float lv[FS * 17];
  if (q < NF) {  // panel for g=q: lv[s*17+k] = v[g, i*500+s, k]
    const int k = tdx & 15, sb = tdx >> 4;
    const float* vb = v + ((size_t)q * TFEAT + (size_t)i * FS) * KD;
    for (int it = 0; it < 32; ++it) {
      int s = it * 16 + sb;
      if (s < FS) lv[s * 17 + k] = vb[(size_t)s * KD + k];
    }
    __syncthreads();
  }
  const float* wf = w + (size_t)i * FS;
  __bf16* base = VtS + ((size_t)i * 16 * NFRG + q) * 512;
  for (int it = 0; it < 4; ++it) {
    int p = it * 256 + tdx;            // (t32,l) pair: 16*64 = 1024
    int t = p >> 6, l = p & 63;
    int r = l >> 2;                    // row within group (= k for q<20)
    int kk = t * 32 + (((l & 3) ^ ((l >> 3) & 3)) << 3);
    bf16x8 h;
#pragma unroll
    for (int e = 0; e < 8; ++e) {
      int s = kk + e;
      float val = 0.f;
      if (s < FS) {
        if (q < NF) val = lv[s * 17 + r];
        else if (r == 0) val = wf[s];
      }
      h[e] = (__bf16)val;
    }
    *(bf16x8*)(base + (size_t)t * (NFRG * 512) + l * 8) = h;
  }
}

// ---------------- K1: per-field GEMM. BM=64, BN=336, BK=64, 8 K-steps, 4 waves.
// Single-buffered m97-style 2-barrier loop; the two 32-wide k-halves use the
// verified R6 sub-layouts (0 bank conflicts). A reg-staged distance-1;
// stage region: glds first, astore reg-wait leaves glds in flight, then
// vmcnt(0)+barrier. LDS 51.2 KB -> 3 blocks/CU. XCD-bijective swizzle.
__global__ __launch_bounds__(256, 3) void k1_gemm(
    const float* __restrict__ x, const __bf16* __restrict__ VtS,
    __bf16* __restrict__ E2, int chunk_base, int tiles) {
  __shared__ __bf16 As[2][64][32];        // k-halves, 8192 B
  __shared__ __bf16 Bs[2][NCOL * 32];     // k-halves, 43008 B

  int bid = blockIdx.x;
  const int nwg = gridDim.x;
  if ((nwg & 7) == 0) {                   // bijective XCD swizzle
    int cpx = nwg >> 3;
    bid = (bid & 7) * cpx + (bid >> 3);
  }
  const int i  = bid / tiles;
  const int tb = bid % tiles;
  const int tid = threadIdx.x;
  const int lane = tid & 63, wid = tid >> 6;
  const int b0 = chunk_base + tb * 64;

  // A stage (per thread): row = tid>>2, 16 f32 cols at (tid&3)*16 within 64-step
  const int arow = tid >> 2;
  const int ac16 = (tid & 3) * 16;
  const int ah  = (tid & 3) >> 1;                  // k-half this thread writes
  const int gh0 = (2 * (tid & 3)) & 3;             // granule-in-half (0 or 2)
  const int rsw = (arow >> 1) & 3;                 // R6 row swizzle
  const float* xrow = x + (size_t)(b0 + arow) * TFEAT + i * FS;
  const __bf16* VtSi = VtS + (size_t)i * 16 * NFRG * 512 + lane * 8;

  auto issueB = [&](int t) {   // stage substeps 2t,2t+1 into halves 0,1
#pragma unroll
    for (int jj = 0; jj < 6; ++jj) {
      int q = wid + 4 * jj;
      if (q < NFRG) {
        gload_lds16(VtSi + ((size_t)(2 * t) * NFRG + q) * 512,
                    (void*)&Bs[0][q * 512]);
        gload_lds16(VtSi + ((size_t)(2 * t + 1) * NFRG + q) * 512,
                    (void*)&Bs[1][q * 512]);
      }
    }
  };

  f32x4 ar_[4];
  auto aload = [&](int t) {
#pragma unroll
    for (int j = 0; j < 4; ++j) {
      int c = t * 64 + ac16 + j * 4;
      if (c > 496) c = 496;              // clamp: junk cols pair with zero B rows
      ar_[j] = *(const f32x4*)(xrow + c);
    }
  };
  auto astore = [&]() {
    bf16x8 h0, h1;
#pragma unroll
    for (int e = 0; e < 4; ++e) {
      h0[e] = (__bf16)ar_[0][e]; h0[4 + e] = (__bf16)ar_[1][e];
      h1[e] = (__bf16)ar_[2][e]; h1[4 + e] = (__bf16)ar_[3][e];
    }
    *(bf16x8*)(&As[ah][arow][((gh0)     ^ rsw) * 8]) = h0;
    *(bf16x8*)(&As[ah][arow][((gh0 + 1) ^ rsw) * 8]) = h1;
  };

  const int nfr = wid ? 5 : 6;
  const int Fbase = wid ? (1 + wid * 5) : 0;
  const int ar = lane & 15, akc = lane >> 4;

  f32x4 acc[4][6];
#pragma unroll
  for (int m = 0; m < 4; ++m)
#pragma unroll
    for (int nf = 0; nf < 6; ++nf) acc[m][nf] = (f32x4){0.f, 0.f, 0.f, 0.f};

  // prologue: tile 0 fully staged
  aload(0);
  issueB(0);
  astore();                              // waits its own aloads (vmcnt covers glds too)
  asm volatile("s_waitcnt vmcnt(0) lgkmcnt(0)" ::: "memory");
  __builtin_amdgcn_s_barrier();

  for (int t = 0; t < 8; ++t) {
    if (t < 7) aload(t + 1);             // 4 dwordx4, age under compute
    __builtin_amdgcn_sched_barrier(0);

#pragma unroll
    for (int ks = 0; ks < 2; ++ks) {
      bf16x8 af[4];
#pragma unroll
      for (int m = 0; m < 4; ++m) {
        int row = m * 16 + ar;
        int pch = akc ^ ((row >> 1) & 3);
        af[m] = *(const bf16x8*)(&As[ks][row][pch * 8]);
      }
#pragma unroll
      for (int nf = 0; nf < 6; ++nf)
        if (nf < nfr) {
          int n_ = (Fbase + nf) * 16 + ar;
          int pc = akc ^ ((n_ >> 1) & 3);
          bf16x8 bfr = *(const bf16x8*)&Bs[ks][n_ * 32 + pc * 8];
#pragma unroll
          for (int m = 0; m < 4; ++m)
            acc[m][nf] = __builtin_amdgcn_mfma_f32_16x16x32_bf16(af[m], bfr,
                                                                 acc[m][nf], 0, 0, 0);
        }
    }
    if (t < 7) {
      __builtin_amdgcn_s_barrier();      // all waves done reading LDS tile t
      issueB(t + 1);                     // 10-12 glds (issued first)
      astore();                          // ds_write; reg-wait leaves glds in flight
      asm volatile("s_waitcnt vmcnt(0) lgkmcnt(0)" ::: "memory");
      __builtin_amdgcn_s_barrier();      // tile t+1 ready
    }
  }

  // epilogue: C/D layout col=lane&15, row=(lane>>4)*4+r
  const int lr4 = akc * 4, lcol = lane & 15;
#pragma unroll
  for (int m = 0; m < 4; ++m)
#pragma unroll
    for (int nf = 0; nf < 6; ++nf)
      if (nf < nfr) {
        int n = (Fbase + nf) * 16 + lcol;
#pragma unroll
        for (int r = 0; r < 4; ++r) {
          int bl = tb * 64 + m * 16 + lr4 + r;
          E2[(size_t)bl * ROWE + i * NCOL + n] = (__bf16)acc[m][nf][r];
        }
      }
}

// ---------------- K2: pair + linear reduction, 1 wave per batch row
__global__ __launch_bounds__(256) void k2_pair(
    const __bf16* __restrict__ E2, float* __restrict__ out, int chunk_base) {
  __shared__ __align__(16) unsigned shw[4][3360];  // 13440 B per wave
  const int tid = threadIdx.x, lane = tid & 63, wid = tid >> 6;
  const int bl = blockIdx.x * 4 + wid;
  const unsigned* src = (const unsigned*)(E2 + (size_t)bl * ROWE);
  for (int it = 0; it < 14; ++it) {
    int idx = it * 64 + lane;             // 16B units; 840 total
    if (idx < 840) {
      u32x4 val = *(const u32x4*)(src + (size_t)idx * 4);
      *(u32x4*)&shw[wid][idx * 4] = val;
    }
  }
  __syncthreads();
  const __bf16* sh = (const __bf16*)shw[wid];
  const int k = lane & 15, g = lane >> 4;
  float sum = 0.f;
  for (int i = g; i < NF; i += 4)
    for (int j = i + 1; j < NF; ++j)
      sum += (float)sh[i * NCOL + j * 16 + k] * (float)sh[j * NCOL + i * 16 + k];
  if (lane < NF) sum += (float)sh[lane * NCOL + 320];   // linear term
#pragma unroll
  for (int off = 32; off; off >>= 1) sum += __shfl_xor(sum, off);
  if (lane == 0) out[chunk_base + bl] = sum;
}

extern "C" void kernel_launch(void* const* d_in, const int* in_sizes, int n_in,
                              void* d_out, int out_size, void* d_ws, size_t ws_size,
                              hipStream_t stream) {
  const float* x = (const float*)d_in[0];
  const float* w = (const float*)d_in[1];
  const float* v = (const float*)d_in[2];
  float* out = (float*)d_out;
  char* ws = (char*)d_ws;

  const size_t vt_bytes = (size_t)NF * 16 * NFRG * 512 * 2;   // 6,881,280
  __bf16* VtS = (__bf16*)ws;
  __bf16* E2 = (__bf16*)(ws + vt_bytes);

  size_t eavail = (ws_size > vt_bytes) ? ws_size - vt_bytes : 0;
  int Bc = NB;
  while (Bc > 64 && (size_t)Bc * ROWE * 2 > eavail) Bc >>= 1;

  prep_vt<<<NF * NFRG, 256, 0, stream>>>(v, w, VtS);
  for (int cb = 0; cb < NB; cb += Bc) {
    int tiles = Bc / 64;
    k1_gemm<<<NF * tiles, 256, 0, stream>>>(x, VtS, E2, cb, tiles);
    k2_pair<<<Bc / 4, 256, 0, stream>>>(E2, out, cb);
  }
}